// Round 9
// baseline (192.183 us; speedup 1.0000x reference)
//
#include <hip/hip_runtime.h>

typedef short v8s __attribute__((ext_vector_type(8)));
typedef float v16f __attribute__((ext_vector_type(16)));

#define N_  16
#define CI_ 32
#define CO_ 64
#define DI  16
#define HI  32
#define WI  32
#define NEGINF (-__builtin_inff())

__device__ __forceinline__ unsigned short f2bf(float f) {
    unsigned int u = __float_as_uint(f);
    unsigned int r = (u + 0x7FFFu + ((u >> 16) & 1u)) >> 16;
    return (unsigned short)r;
}

// async 16B global->LDS (LDS dst = wave-uniform base + lane*16)
__device__ __forceinline__ void gld16(const void* g, void* l) {
    __builtin_amdgcn_global_load_lds(
        (const __attribute__((address_space(1))) void*)g,
        (__attribute__((address_space(3))) void*)l, 16, 0, 0);
}

// Per-class base offsets in halves: 2048 * cumsum(taps).
__constant__ int O64c[9] = {0, 55296, 92160, 129024, 153600, 190464, 215040, 239616, 256000};

// R20 prep: x->xp unchanged; wt repacked for 32x32x16 B fragments:
// halves off = tap*2048 + p*1024 + tile*512 + lane*8 + j,
//   co = tile*32 + (lane&31), ci = p*16 + (lane>>5)*8 + j.
// Ledger: R15/16 coop-mono refuted (harness window + convoy); R17 nt-half
// refuted (2x LDS); R18 deep-B + R19 de-phase null. Seven schedules pinned
// at ~1.25PF = half peak -> R20 tests MFMA ISSUE-SLOT bound via 32x32x16
// (20 instr/tap vs 36 at same FLOPs).
__global__ void prep(const float* __restrict__ x, const float* __restrict__ w,
                     unsigned short* __restrict__ xp, unsigned short* __restrict__ wt,
                     float* __restrict__ out, int do_x) {
    if (blockIdx.x < 1088) {
        if (!do_x) return;
        __shared__ __align__(16) unsigned short tl[8192];   // [h32][w32][c8] bf16
        const int bi = blockIdx.x;
        const int pd = bi % 17;
        const int cg = (bi / 17) & 3;
        const int n  = bi / 68;
        if (pd > 0) {
            const int c = threadIdx.x >> 5;       // 0..7
            const int ww = threadIdx.x & 31;      // 0..31
            const float* xc = x + (((size_t)(n * 32 + cg * 8 + c) * 16 + (pd - 1)) * 32) * 32;
            #pragma unroll
            for (int h = 0; h < 32; ++h)
                tl[(h * 32 + ww) * 8 + c] = f2bf(xc[h * 32 + ww]);
        }
        __syncthreads();
        unsigned short* xpo = xp + (size_t)bi * 8448;   // 32*33*8
        for (int o = threadIdx.x; o < 1056; o += 256) {
            int ph = o / 33, pw = o - ph * 33;
            v8s v;
            if (pd == 0 || ph == 0 || pw == 0) v = (v8s){0, 0, 0, 0, 0, 0, 0, 0};
            else v = *(const v8s*)&tl[((ph - 1) * 32 + pw - 1) * 8];
            *(v8s*)(xpo + o * 8) = v;
        }
    } else {
        if (blockIdx.x == 1088 && threadIdx.x < 64) {
            int tb = 1536 + threadIdx.x;
            int whalf = tb & 1, hj = (tb >> 1) % 10, dj = (tb / 20) % 5, n = tb / 100;
            float* o = out + (((size_t)(n * 5 + dj) * 10 + hj) * 10 + whalf * 5);
            #pragma unroll
            for (int j = 0; j < 5; ++j) o[j] = 0.f;
        }
        int u = (blockIdx.x - 1088) * 256 + threadIdx.x;
        if (u >= 256000) return;
        int r = 0;
        #pragma unroll
        for (int i = 1; i < 8; ++i) r += (u >= O64c[i]);
        const int rd = r >> 2, rh = (r >> 1) & 1, rw = r & 1;
        const int nh = rh ? 2 : 3, nw = rw ? 2 : 3;
        int t2   = u - O64c[r];
        int j    = t2 & 7;
        int lane = (t2 >> 3) & 63;
        int tile = (t2 >> 9) & 1;
        int p    = (t2 >> 10) & 1;
        int tap  = t2 >> 11;
        int co = tile * 32 + (lane & 31);
        int ci = p * 16 + (lane >> 5) * 8 + j;
        int jw = tap % nw;
        int jh = (tap / nw) % nh;
        int jd = tap / (nw * nh);
        int kd = rd + 2 * jd, kh = rh + 2 * jh, kw = rw + 2 * jw;
        wt[u] = f2bf(w[(ci * CO_ + co) * 125 + kd * 25 + kh * 5 + kw]);
    }
}

// Row-pair table: pairs (hi=0,hi=1) = (0,576),(1728,2880),(3456,288),
// (1440,2016),(3168,3168). Last pair duplicates row 3168 -> idempotent
// under the pool max (pads M 9->10 rows, 11% FLOP waste).
__constant__ int RO2e[10] = {0, 576, 1728, 2880, 3456, 288, 1440, 2016, 3168, 3168};

// R20 main body: 32x32x16 MFMA. M=32 = 2 packed RO rows x 16 spatial,
// N=32 per tile (2 tiles = co 0..63), K=16 x 2 chained steps (cg pairs).
// acc[5][2] v16f = 160 regs. 20 MFMA/tap vs 36 (same FLOPs).
__device__ __forceinline__ void run_class_f(
        const unsigned short* __restrict__ xs,
        int baseP0, int baseP1,                  // lane byte base, kstep 0/1
        const int (&ROl)[5],                     // per-lane row-pair offsets
        const unsigned short* __restrict__ wcls, // wt + O64[r] + lane*8
        const int taps, const int nw, const int nh,
        unsigned Bm0, unsigned Bm1, bool hHi, float (&pmax)[2][2][2])
{
    const char* xb = (const char*)xs;

    v16f acc[5][2];
    #pragma unroll
    for (int pr = 0; pr < 5; ++pr) {
        acc[pr][0] = (v16f)0.f;
        acc[pr][1] = (v16f)0.f;
    }

    // B fragment offsets (halves): f = p*2+tile -> {p0t0,p0t1,p1t0,p1t1}
    v8s B0[4], B1[4];
    #pragma unroll
    for (int f = 0; f < 4; ++f) B0[f] = *(const v8s*)(wcls + f * 512);

    int aoff = 0, jw = 0, jh = 0;
    auto adv = [&]() {
        aoff += 16; ++jw;
        if (jw == nw) { jw = 0; aoff += 288 - 16 * nw; ++jh;
            if (jh == nh) { jh = 0; aoff += 1440 - 288 * nh; } }
    };
    auto comp = [&](const v8s (&B)[4]) {
        __builtin_amdgcn_s_setprio(1);
        #pragma unroll
        for (int pr = 0; pr < 5; ++pr) {
            v8s a0 = *(const v8s*)(xb + baseP0 + ROl[pr] - aoff);
            v8s a1 = *(const v8s*)(xb + baseP1 + ROl[pr] - aoff);
            acc[pr][0] = __builtin_amdgcn_mfma_f32_32x32x16_bf16(a0, B[0], acc[pr][0], 0, 0, 0);
            acc[pr][1] = __builtin_amdgcn_mfma_f32_32x32x16_bf16(a0, B[1], acc[pr][1], 0, 0, 0);
            acc[pr][0] = __builtin_amdgcn_mfma_f32_32x32x16_bf16(a1, B[2], acc[pr][0], 0, 0, 0);
            acc[pr][1] = __builtin_amdgcn_mfma_f32_32x32x16_bf16(a1, B[3], acc[pr][1], 0, 0, 0);
        }
        __builtin_amdgcn_s_setprio(0);
    };
    auto ldB = [&](v8s (&B)[4], int t) {
        #pragma unroll
        for (int f = 0; f < 4; ++f)
            B[f] = *(const v8s*)(wcls + t * 2048 + f * 512);
    };

    int s = 0;
    while (s + 2 <= taps) {
        ldB(B1, s + 1);
        comp(B0); adv();
        if (s + 2 < taps) ldB(B0, s + 2);
        comp(B1); adv();
        s += 2;
    }
    if (s < taps) comp(B0);

    // fold: D row = (reg&3) + 8*(reg>>2) + 4*h; spatial m = row&15,
    // q_m = h + 2*((reg>>2)&1), regm = reg&3. m==15 only at h=1,qi=1,regm=3.
    #pragma unroll
    for (int tl = 0; tl < 2; ++tl) {
        #pragma unroll
        for (int reg = 0; reg < 16; ++reg) {
            float v = acc[0][tl][reg];
            #pragma unroll
            for (int pr = 1; pr < 5; ++pr) v = fmaxf(v, acc[pr][tl][reg]);
            const int qi = (reg >> 2) & 1;
            const int regm = reg & 3;
            if (hHi && qi == 1 && regm == 3) v = NEGINF;   // skip m==15
            const unsigned bm = qi ? Bm1 : Bm0;
            const bool bB = (bm >> regm) & 1u;
            if (qi == 0) {
                pmax[tl][0][0] = fmaxf(pmax[tl][0][0], bB ? NEGINF : v);
                pmax[tl][0][1] = fmaxf(pmax[tl][0][1], bB ? v : NEGINF);
            } else {
                pmax[tl][1][0] = fmaxf(pmax[tl][1][0], bB ? NEGINF : v);
                pmax[tl][1][1] = fmaxf(pmax[tl][1][1], bB ? v : NEGINF);
            }
        }
    }
}

// tail body: single 32-co tile (tile = sub). acc[5] v16f = 80 regs.
__device__ __forceinline__ void run_class_t(
        const unsigned short* __restrict__ xs,
        int baseP0, int baseP1,
        const int (&ROl)[5],
        const unsigned short* __restrict__ wcls, // wt + O64[r] + sub*512 + lane*8
        const int taps, const int nw, const int nh,
        unsigned Bm0, unsigned Bm1, bool hHi, float (&pm)[2][2])
{
    const char* xb = (const char*)xs;

    v16f acc[5];
    #pragma unroll
    for (int pr = 0; pr < 5; ++pr) acc[pr] = (v16f)0.f;

    v8s B0[2], B1[2];
    B0[0] = *(const v8s*)(wcls + 0);
    B0[1] = *(const v8s*)(wcls + 1024);

    int aoff = 0, jw = 0, jh = 0;
    auto adv = [&]() {
        aoff += 16; ++jw;
        if (jw == nw) { jw = 0; aoff += 288 - 16 * nw; ++jh;
            if (jh == nh) { jh = 0; aoff += 1440 - 288 * nh; } }
    };
    auto comp = [&](const v8s (&B)[2]) {
        #pragma unroll
        for (int pr = 0; pr < 5; ++pr) {
            v8s a0 = *(const v8s*)(xb + baseP0 + ROl[pr] - aoff);
            v8s a1 = *(const v8s*)(xb + baseP1 + ROl[pr] - aoff);
            acc[pr] = __builtin_amdgcn_mfma_f32_32x32x16_bf16(a0, B[0], acc[pr], 0, 0, 0);
            acc[pr] = __builtin_amdgcn_mfma_f32_32x32x16_bf16(a1, B[1], acc[pr], 0, 0, 0);
        }
    };
    auto ldB = [&](v8s (&B)[2], int t) {
        B[0] = *(const v8s*)(wcls + t * 2048 + 0);
        B[1] = *(const v8s*)(wcls + t * 2048 + 1024);
    };

    int s = 0;
    while (s + 2 <= taps) {
        ldB(B1, s + 1);
        comp(B0); adv();
        if (s + 2 < taps) ldB(B0, s + 2);
        comp(B1); adv();
        s += 2;
    }
    if (s < taps) comp(B0);

    #pragma unroll
    for (int reg = 0; reg < 16; ++reg) {
        float v = acc[0][reg];
        #pragma unroll
        for (int pr = 1; pr < 5; ++pr) v = fmaxf(v, acc[pr][reg]);
        const int qi = (reg >> 2) & 1;
        const int regm = reg & 3;
        if (hHi && qi == 1 && regm == 3) v = NEGINF;
        const unsigned bm = qi ? Bm1 : Bm0;
        const bool bB = (bm >> regm) & 1u;
        if (qi == 0) {
            pm[0][0] = fmaxf(pm[0][0], bB ? NEGINF : v);
            pm[0][1] = fmaxf(pm[0][1], bB ? v : NEGINF);
        } else {
            pm[1][0] = fmaxf(pm[1][0], bB ? NEGINF : v);
            pm[1][1] = fmaxf(pm[1][1], bB ? v : NEGINF);
        }
    }
}

// R20 structure: 1536 full blocks (3 rounds at 2/CU) + 128 half-tile tail
// sub-blocks. P2 overlay: [wv4][q4][co64][2] floats (8KB).
template<bool PRE>
__global__ __launch_bounds__(256, 2)
void fused_main(const float* __restrict__ x, const unsigned short* __restrict__ xp,
                const unsigned short* __restrict__ wt,
                const float* __restrict__ bias, float* __restrict__ out) {
    __shared__ __align__(16) char smem[28800];
    unsigned short* xs = (unsigned short*)smem;   // [g4][id'5][ih'5][iw'18][c8]
    float* P = (float*)smem;                      // P2 overlay (8KB)
    float* Y = (float*)(smem + 9472);             // [co64][wjl5]

    const int b = blockIdx.x;
    const bool tail = (b >= 1536);
    int tile, sub;
    if (tail) { int u = b - 1536; tile = 1536 + (u >> 1); sub = u & 1; }
    else      { tile = b; sub = 0; }

    const int whalf = tile & 1;
    const int hj = (tile >> 1) % 10;
    const int dj = (tile / 20) % 5;
    const int n  = tile / 100;

    const int lane = threadIdx.x & 63;
    const int wv   = threadIdx.x >> 6;

    if (PRE) {
        // DMA staging: 1800 chunks x 16B from pre-padded xp
        const int t = threadIdx.x;
        #pragma unroll
        for (int i = 0; i < 8; ++i) {
            int c = i * 256 + t;
            if (c < 1800) {
                int row = c / 18;
                int iwc = c - row * 18;
                int cg  = row / 25;
                int rr  = row - cg * 25;
                int idl = rr / 5;
                int ihl = rr - idl * 5;
                size_t goff = ((((size_t)((n * 4 + cg) * 17 + 3 * dj + idl)) * 32
                                + 3 * hj + ihl) * 33 + 15 * whalf + iwc) * 8;
                gld16(xp + goff, smem + i * 4096 + wv * 1024);
            }
        }
    } else {
        const int id0 = 3 * dj - 1, ih0 = 3 * hj - 1, iwb = 15 * whalf - 1;
        const float* xn = x + (size_t)n * (CI_ * DI * HI * WI);
        for (int e = threadIdx.x; e < 14400; e += 256) {
            int ci   = e / 450;
            int rem  = e - ci * 450;
            int idp  = rem / 90;
            int rem2 = rem - idp * 90;
            int ihp  = rem2 / 18;
            int iwp  = rem2 - ihp * 18;
            int id = id0 + idp, ih = ih0 + ihp, iw = iwb + iwp;
            float v = 0.f;
            if (id >= 0 && ih >= 0 && iw >= 0)
                v = xn[((ci * DI + id) * HI + ih) * WI + iw];
            xs[(ci >> 3) * 3600 + idp * 720 + ihp * 144 + iwp * 8 + (ci & 7)] = f2bf(v);
        }
    }
    __syncthreads();

    // 32x32 lane geometry
    const int h    = lane >> 5;          // k-half / q-low
    const int r32  = lane & 31;          // D col within tile
    const int hi   = r32 >> 4;           // row-pair member
    const int mrow = r32 & 15;           // spatial row
    const int baseP0 = (0 + h) * 7200 + (mrow + 2) * 16 + 3456;  // kstep 0: cg h
    const int baseP1 = (2 + h) * 7200 + (mrow + 2) * 16 + 3456;  // kstep 1: cg 2+h
    int ROl[5];
    #pragma unroll
    for (int pr = 0; pr < 5; ++pr) ROl[pr] = RO2e[pr * 2 + hi];

    const unsigned Bm0 = (0x0EC8u >> (h * 4)) & 0xFu;          // q = h
    const unsigned Bm1 = (0x0EC8u >> ((h + 2) * 4)) & 0xFu;    // q = h+2
    const bool hHi = (h == 1);

    static constexpr int tapsT[8] = {27, 18, 18, 12, 18, 12, 12, 8};
    static constexpr int O64[8]   = {0, 55296, 92160, 129024, 153600, 190464, 215040, 239616};
    static constexpr int nwT[8]   = {3, 2, 3, 2, 3, 2, 3, 2};
    static constexpr int nhT[8]   = {3, 3, 2, 2, 3, 3, 2, 2};
    static constexpr int uOff[5] = {0, 2, 4, 6, 8};
    static constexpr int uR[8]   = {0, 7,  1, 3,  2, 5,  4, 6};

    static constexpr int wjAt[4] = {0, 1, 2, 4};
    static constexpr int wjBt[4] = {1, 2, 3, 5};

    const int u0 = uOff[wv], u1 = uOff[wv + 1];

    if (!tail) {
        float pmax[2][2][2];   // [tile][qi][slot]
        #pragma unroll
        for (int tl = 0; tl < 2; ++tl)
            #pragma unroll
            for (int qi = 0; qi < 2; ++qi) { pmax[tl][qi][0] = NEGINF; pmax[tl][qi][1] = NEGINF; }

        #pragma unroll 1
        for (int iu = u0; iu < u1; ++iu) {
            const int r = uR[iu];
            run_class_f(xs, baseP0, baseP1, ROl, wt + O64[r] + lane * 8,
                        tapsT[r], nwT[r], nhT[r], Bm0, Bm1, hHi, pmax);
        }

        // ---- cross-wave reduction: P2[wv][q][co][slot] ----
        __syncthreads();
        #pragma unroll
        for (int tl = 0; tl < 2; ++tl) {
            #pragma unroll
            for (int qi = 0; qi < 2; ++qi) {
                const int q = h + 2 * qi;
                const int co = tl * 32 + r32;
                const int idx = ((wv * 4 + q) * 64 + co) * 2;
                P[idx + 0] = pmax[tl][qi][0];
                P[idx + 1] = pmax[tl][qi][1];
            }
        }
        __syncthreads();

        for (int oi = threadIdx.x; oi < 320; oi += 256) {
            int co = oi / 5;
            int wjl = oi - co * 5;
            float v = NEGINF;
            #pragma unroll
            for (int w = 0; w < 4; ++w) {
                #pragma unroll
                for (int qq = 0; qq < 4; ++qq) {
                    const float* pp = &P[((w * 4 + qq) * 64 + co) * 2];
                    if (wjAt[qq] == wjl) v = fmaxf(v, pp[0]);
                    if (wjBt[qq] == wjl) v = fmaxf(v, pp[1]);
                }
            }
            Y[co * 5 + wjl] = v + bias[co];
        }
        __syncthreads();

        // channel-sum: wave 0, lane = co; 5 butterfly reductions over 64 lanes
        if (wv == 0) {
            float vy[5];
            #pragma unroll
            for (int wjl = 0; wjl < 5; ++wjl) vy[wjl] = Y[lane * 5 + wjl];
            #pragma unroll
            for (int wjl = 0; wjl < 5; ++wjl) {
                float v = vy[wjl];
                #pragma unroll
                for (int off = 32; off > 0; off >>= 1)
                    v += __shfl_down(v, off, 64);
                if (lane == 0)
                    out[((n * 5 + dj) * 10 + hj) * 10 + whalf * 5 + wjl] = v;
            }
        }
    } else {
        // ---- tail sub-block: one 32-co tile (tile = sub), all 8 classes ----
        float pm[2][2];   // [qi][slot]
        pm[0][0] = NEGINF; pm[0][1] = NEGINF;
        pm[1][0] = NEGINF; pm[1][1] = NEGINF;

        #pragma unroll 1
        for (int iu = u0; iu < u1; ++iu) {
            const int r = uR[iu];
            run_class_t(xs, baseP0, baseP1, ROl, wt + O64[r] + sub * 512 + lane * 8,
                        tapsT[r], nwT[r], nhT[r], Bm0, Bm1, hHi, pm);
        }

        // P2t[wv][q][co32][slot]
        __syncthreads();
        #pragma unroll
        for (int qi = 0; qi < 2; ++qi) {
            const int q = h + 2 * qi;
            const int idx = ((wv * 4 + q) * 32 + r32) * 2;
            P[idx + 0] = pm[qi][0];
            P[idx + 1] = pm[qi][1];
        }
        __syncthreads();

        // wave0: lane < 32 holds co = sub*32 + lane; shuffle-sum all 64 lanes.
        if (wv == 0) {
            const bool valid = (lane < 32);
            const int cl = lane & 31;
            float vy[5];
            #pragma unroll
            for (int wjl = 0; wjl < 5; ++wjl) vy[wjl] = NEGINF;
            #pragma unroll
            for (int w = 0; w < 4; ++w) {
                #pragma unroll
                for (int qq = 0; qq < 4; ++qq) {
                    const float* pp = &P[((w * 4 + qq) * 32 + cl) * 2];
                    float a = pp[0], bv = pp[1];
                    #pragma unroll
                    for (int wjl = 0; wjl < 5; ++wjl) {
                        if (wjAt[qq] == wjl) vy[wjl] = fmaxf(vy[wjl], a);
                        if (wjBt[qq] == wjl) vy[wjl] = fmaxf(vy[wjl], bv);
                    }
                }
            }
            #pragma unroll
            for (int wjl = 0; wjl < 5; ++wjl) {
                float v = valid ? (vy[wjl] + bias[sub * 32 + cl]) : 0.f;
                #pragma unroll
                for (int off = 32; off > 0; off >>= 1)
                    v += __shfl_down(v, off, 64);
                if (lane == 0)
                    atomicAdd(&out[((n * 5 + dj) * 10 + hj) * 10 + whalf * 5 + wjl], v);
            }
        }
    }
}

extern "C" void kernel_launch(void* const* d_in, const int* in_sizes, int n_in,
                              void* d_out, int out_size, void* d_ws, size_t ws_size,
                              hipStream_t stream) {
    const float* x    = (const float*)d_in[0];
    const float* w    = (const float*)d_in[1];
    const float* bias = (const float*)d_in[2];
    float*       out  = (float*)d_out;
    unsigned short* wt = (unsigned short*)d_ws;                        // 512000 B
    unsigned short* xp = (unsigned short*)((char*)d_ws + 512512);      // 18,382,848 B
    const size_t XP_NEED = 512512 + 18382848;
    const int do_x = (ws_size >= XP_NEED) ? 1 : 0;

    prep<<<dim3(2088), 256, 0, stream>>>(x, w, xp, wt, out, do_x);
    if (do_x)
        fused_main<true ><<<dim3(1664), 256, 0, stream>>>(x, xp, wt, bias, out);
    else
        fused_main<false><<<dim3(1664), 256, 0, stream>>>(x, xp, wt, bias, out);
}

// Round 10
// 174.484 us; speedup vs baseline: 1.1014x; 1.1014x over previous
//
#include <hip/hip_runtime.h>

typedef short v8s __attribute__((ext_vector_type(8)));
typedef float v4f __attribute__((ext_vector_type(4)));

#define N_  16
#define CI_ 32
#define CO_ 64
#define DI  16
#define HI  32
#define WI  32
#define NEGINF (-__builtin_inff())

__device__ __forceinline__ unsigned short f2bf(float f) {
    unsigned int u = __float_as_uint(f);
    unsigned int r = (u + 0x7FFFu + ((u >> 16) & 1u)) >> 16;
    return (unsigned short)r;
}

// async 16B global->LDS (LDS dst = wave-uniform base + lane*16)
__device__ __forceinline__ void gld16(const void* g, void* l) {
    __builtin_amdgcn_global_load_lds(
        (const __attribute__((address_space(1))) void*)g,
        (__attribute__((address_space(3))) void*)l, 16, 0, 0);
}

// Per-class base offsets in halves: 2048 * cumsum(taps).
__constant__ int O64c[9] = {0, 55296, 92160, 129024, 153600, 190464, 215040, 239616, 256000};

// Fused prep (R9/R11-proven) + R13 tail-tile output zeroing.
// SESSION LEDGER (final): R14 parity-fused @ 2 blk/CU is the best verified
// structure (fused_main ~106us, MfmaUtil ~48.5%). Refuted alternatives:
//  R13 parity-split 3blk (B x2 re-reads, 117us) | R15/R16 coop-mono
//  (window is harness-fixed; grid.sync convoys, 218us) | R17 nt-half 3blk
//  (A x2 ds_reads, LDS ~85% busy, 111us) | R18 deep-B+setprio (null) |
//  R19 SIMD de-phase (null) | R20 32x32x16 shape (MFMA-busy UP 51->62us,
//  124us). Structural wall: 256-reg waves vs 512-reg/SIMD pool = 2
//  waves/SIMD; acc-splitting to 3 waves duplicates operand traffic and
//  measured worse; at 2 waves/SIMD LDS-fed MFMA duty ~50% with correlated
//  stalls on the shared LDS unit. Floor ~= 57us/0.5 ~= 105us = R14.
__global__ void prep(const float* __restrict__ x, const float* __restrict__ w,
                     unsigned short* __restrict__ xp, unsigned short* __restrict__ wt,
                     float* __restrict__ out, int do_x) {
    if (blockIdx.x < 1088) {
        if (!do_x) return;
        __shared__ __align__(16) unsigned short tl[8192];   // [h32][w32][c8] bf16
        const int bi = blockIdx.x;
        const int pd = bi % 17;
        const int cg = (bi / 17) & 3;
        const int n  = bi / 68;
        if (pd > 0) {
            const int c = threadIdx.x >> 5;       // 0..7
            const int ww = threadIdx.x & 31;      // 0..31
            const float* xc = x + (((size_t)(n * 32 + cg * 8 + c) * 16 + (pd - 1)) * 32) * 32;
            #pragma unroll
            for (int h = 0; h < 32; ++h)
                tl[(h * 32 + ww) * 8 + c] = f2bf(xc[h * 32 + ww]);
        }
        __syncthreads();
        unsigned short* xpo = xp + (size_t)bi * 8448;   // 32*33*8
        for (int o = threadIdx.x; o < 1056; o += 256) {
            int ph = o / 33, pw = o - ph * 33;
            v8s v;
            if (pd == 0 || ph == 0 || pw == 0) v = (v8s){0, 0, 0, 0, 0, 0, 0, 0};
            else v = *(const v8s*)&tl[((ph - 1) * 32 + pw - 1) * 8];
            *(v8s*)(xpo + o * 8) = v;
        }
    } else {
        if (blockIdx.x == 1088 && threadIdx.x < 64) {
            // zero tail-tile outputs (accumulated by atomicAdd in fused_main)
            int tb = 1536 + threadIdx.x;
            int whalf = tb & 1, hj = (tb >> 1) % 10, dj = (tb / 20) % 5, n = tb / 100;
            float* o = out + (((size_t)(n * 5 + dj) * 10 + hj) * 10 + whalf * 5);
            #pragma unroll
            for (int j = 0; j < 5; ++j) o[j] = 0.f;
        }
        int u = (blockIdx.x - 1088) * 256 + threadIdx.x;
        if (u >= 256000) return;
        int r = 0;
        #pragma unroll
        for (int i = 1; i < 8; ++i) r += (u >= O64c[i]);
        const int rd = r >> 2, rh = (r >> 1) & 1, rw = r & 1;
        const int nh = rh ? 2 : 3, nw = rw ? 2 : 3;
        int t2 = u - O64c[r];
        int j   = t2 & 7;
        int l   = (t2 >> 3) & 15;
        int q   = (t2 >> 7) & 3;
        int nt  = (t2 >> 9) & 3;
        int tap = t2 >> 11;
        int co = nt * 16 + l;
        int ci = q * 8 + j;
        int jw = tap % nw;
        int jh = (tap / nw) % nh;
        int jd = tap / (nw * nh);
        int kd = rd + 2 * jd, kh = rh + 2 * jh, kw = rw + 2 * jw;
        wt[u] = f2bf(w[(ci * CO_ + co) * 125 + kd * 25 + kh * 5 + kw]);
    }
}

// R14: PARITY-FUSED class body. Both parities of a class consume the SAME
// B stream (B depends only on class/tap/nt), so fusing them:
//  - halves B re-reads from L2 (1MB -> 0.5MB per block),
//  - doubles MFMA cover per B batch (36 MFMA ~ 175cyc vs ~200cyc L2 latency),
//  - keeps MFMA:ds_read at 4:1 (9 rows/tap = old 5+4).
// Cost: acc[9][4] = 144 AGPR -> 2 blocks/CU (launch_bounds(256,2)).
// Row byte-offsets: p0 rows {0,576,1728,2880,3456}, p1 rows {288,1440,2016,3168}.
__device__ __forceinline__ void run_class_f(
        const unsigned short* __restrict__ xs,   // LDS patch
        int laneAB,                              // byte addr: q*7200 + (l+2)*16 + 3456
        const unsigned short* __restrict__ wcls, // wt + O64[r] + lane*8 (swizzled)
        const int taps, const int nw, const int nh,
        unsigned Bm, bool isQ3, float (&pmax)[4][2])
{
    const char* xb = (const char*)xs;

    v4f acc[9][4];
    #pragma unroll
    for (int t = 0; t < 9; ++t)
        #pragma unroll
        for (int nt = 0; nt < 4; ++nt)
            acc[t][nt] = (v4f){0.f, 0.f, 0.f, 0.f};

    v8s B0[4], B1[4];
    #pragma unroll
    for (int nt = 0; nt < 4; ++nt) B0[nt] = *(const v8s*)(wcls + nt * 512);

    int aoff = 0, jw = 0, jh = 0;
    auto adv = [&]() {
        aoff += 16; ++jw;
        if (jw == nw) { jw = 0; aoff += 288 - 16 * nw; ++jh;
            if (jh == nh) { jh = 0; aoff += 1440 - 288 * nh; } }
    };
    auto comp = [&](const v8s (&B)[4]) {
        const int va = laneAB - aoff;
        static constexpr int RO[9] = {0, 576, 1728, 2880, 3456, 288, 1440, 2016, 3168};
        #pragma unroll
        for (int rr = 0; rr < 9; ++rr) {
            v8s a = *(const v8s*)(xb + va + RO[rr]);
            #pragma unroll
            for (int nt = 0; nt < 4; ++nt)
                acc[rr][nt] = __builtin_amdgcn_mfma_f32_16x16x32_bf16(a, B[nt], acc[rr][nt], 0, 0, 0);
        }
    };

    int s = 0;
    while (s + 2 <= taps) {
        #pragma unroll
        for (int nt = 0; nt < 4; ++nt)
            B1[nt] = *(const v8s*)(wcls + ((s + 1) * 4 + nt) * 512);
        comp(B0); adv();
        if (s + 2 < taps) {
            #pragma unroll
            for (int nt = 0; nt < 4; ++nt)
                B0[nt] = *(const v8s*)(wcls + ((s + 2) * 4 + nt) * 512);
        }
        comp(B1); adv();
        s += 2;
    }
    if (s < taps) comp(B0);

    // fold: max over all 9 rows (both parities feed the same pmax slots)
    #pragma unroll
    for (int nt = 0; nt < 4; ++nt) {
        #pragma unroll
        for (int reg = 0; reg < 4; ++reg) {
            float v = acc[0][nt][reg];
            #pragma unroll
            for (int rr = 1; rr < 9; ++rr) v = fmaxf(v, acc[rr][nt][reg]);
            if (reg == 3) v = isQ3 ? NEGINF : v;   // skip m==15
            const bool bB = (Bm >> reg) & 1u;
            pmax[nt][0] = fmaxf(pmax[nt][0], bB ? NEGINF : v);
            pmax[nt][1] = fmaxf(pmax[nt][1], bB ? v : NEGINF);
        }
    }
}

// R14 tail body: parity-fused, single-nt slice. acc[9] = 36 regs.
__device__ __forceinline__ void run_class_t(
        const unsigned short* __restrict__ xs,
        int laneAB,
        const unsigned short* __restrict__ wcls, // wt + O64[r] + sub*512 + lane*8
        const int taps, const int nw, const int nh,
        unsigned Bm, bool isQ3, float (&pmax)[2])
{
    const char* xb = (const char*)xs;

    v4f acc[9];
    #pragma unroll
    for (int t = 0; t < 9; ++t) acc[t] = (v4f){0.f, 0.f, 0.f, 0.f};

    v8s B0 = *(const v8s*)(wcls);
    v8s B1;

    int aoff = 0, jw = 0, jh = 0;
    auto adv = [&]() {
        aoff += 16; ++jw;
        if (jw == nw) { jw = 0; aoff += 288 - 16 * nw; ++jh;
            if (jh == nh) { jh = 0; aoff += 1440 - 288 * nh; } }
    };
    auto comp = [&](v8s B) {
        const int va = laneAB - aoff;
        static constexpr int RO[9] = {0, 576, 1728, 2880, 3456, 288, 1440, 2016, 3168};
        #pragma unroll
        for (int rr = 0; rr < 9; ++rr) {
            v8s a = *(const v8s*)(xb + va + RO[rr]);
            acc[rr] = __builtin_amdgcn_mfma_f32_16x16x32_bf16(a, B, acc[rr], 0, 0, 0);
        }
    };

    int s = 0;
    while (s + 2 <= taps) {
        B1 = *(const v8s*)(wcls + (s + 1) * 2048);
        comp(B0); adv();
        if (s + 2 < taps) B0 = *(const v8s*)(wcls + (s + 2) * 2048);
        comp(B1); adv();
        s += 2;
    }
    if (s < taps) comp(B0);

    #pragma unroll
    for (int reg = 0; reg < 4; ++reg) {
        float v = acc[0][reg];
        #pragma unroll
        for (int rr = 1; rr < 9; ++rr) v = fmaxf(v, acc[rr][reg]);
        if (reg == 3) v = isQ3 ? NEGINF : v;
        const bool bB = (Bm >> reg) & 1u;
        pmax[0] = fmaxf(pmax[0], bB ? NEGINF : v);
        pmax[1] = fmaxf(pmax[1], bB ? v : NEGINF);
    }
}

// R14 structure (session best, 174.68us total): parity-fused passes,
// 2 blocks/CU residency. 1536 full blocks = exactly 3 rounds of 512 slots
// at 2/CU; 256 tail sub-blocks (nt-sliced) appended. 8 fused units
// partitioned {c0,c7},{c1,c3},{c2,c5},{c4,c6} = {315,270,270,270}.
template<bool PRE>
__global__ __launch_bounds__(256, 2)
void fused_main(const float* __restrict__ x, const unsigned short* __restrict__ xp,
                const unsigned short* __restrict__ wt,
                const float* __restrict__ bias, float* __restrict__ out) {
    __shared__ __align__(16) char smem[28800];
    unsigned short* xs = (unsigned short*)smem;   // [g4][id'5][ih'5][iw'18][c8]
    float* P = (float*)smem;                      // [wave4][q4][l16][9] (8 used + pad)
    float* Y = (float*)(smem + 9472);             // [co64][wjl5]

    const int b = blockIdx.x;
    const bool tail = (b >= 1536);
    int tile, sub;
    if (tail) { int u = b - 1536; tile = 1536 + (u >> 2); sub = u & 3; }
    else      { tile = b; sub = 0; }

    const int whalf = tile & 1;
    const int hj = (tile >> 1) % 10;
    const int dj = (tile / 20) % 5;
    const int n  = tile / 100;

    const int lane = threadIdx.x & 63;
    const int wv   = threadIdx.x >> 6;

    if (PRE) {
        // DMA staging: 1800 chunks x 16B from pre-padded xp
        const int t = threadIdx.x;
        #pragma unroll
        for (int i = 0; i < 8; ++i) {
            int c = i * 256 + t;
            if (c < 1800) {
                int row = c / 18;
                int iwc = c - row * 18;
                int cg  = row / 25;
                int rr  = row - cg * 25;
                int idl = rr / 5;
                int ihl = rr - idl * 5;
                size_t goff = ((((size_t)((n * 4 + cg) * 17 + 3 * dj + idl)) * 32
                                + 3 * hj + ihl) * 33 + 15 * whalf + iwc) * 8;
                gld16(xp + goff, smem + i * 4096 + wv * 1024);
            }
        }
    } else {
        const int id0 = 3 * dj - 1, ih0 = 3 * hj - 1, iwb = 15 * whalf - 1;
        const float* xn = x + (size_t)n * (CI_ * DI * HI * WI);
        for (int e = threadIdx.x; e < 14400; e += 256) {
            int ci   = e / 450;
            int rem  = e - ci * 450;
            int idp  = rem / 90;
            int rem2 = rem - idp * 90;
            int ihp  = rem2 / 18;
            int iwp  = rem2 - ihp * 18;
            int id = id0 + idp, ih = ih0 + ihp, iw = iwb + iwp;
            float v = 0.f;
            if (id >= 0 && ih >= 0 && iw >= 0)
                v = xn[((ci * DI + id) * HI + ih) * WI + iw];
            xs[(ci >> 3) * 3600 + idp * 720 + ihp * 144 + iwp * 8 + (ci & 7)] = f2bf(v);
        }
    }
    __syncthreads();

    const int l = lane & 15, q = lane >> 4;
    const int laneAB = q * 7200 + (l + 2) * 16 + 3456;  // bytes

    static constexpr int tapsT[8] = {27, 18, 18, 12, 18, 12, 12, 8};
    static constexpr int O64[8]   = {0, 55296, 92160, 129024, 153600, 190464, 215040, 239616};
    static constexpr int nwT[8]   = {3, 2, 3, 2, 3, 2, 3, 2};
    static constexpr int nhT[8]   = {3, 3, 2, 2, 3, 3, 2, 2};
    // fused unit lists per wave; unit cost = taps*9 rows:
    // w0: c0,c7 = 243+72 = 315 ; w1: c1,c3 = 270 ; w2: c2,c5 = 270 ; w3: c4,c6 = 270
    static constexpr int uOff[5] = {0, 2, 4, 6, 8};
    static constexpr int uR[8]   = {0, 7,  1, 3,  2, 5,  4, 6};

    static constexpr int wjAt[4] = {0, 1, 2, 4};
    static constexpr int wjBt[4] = {1, 2, 3, 5};

    const unsigned Bm = (0x0EC8u >> (q << 2)) & 0xFu;
    const bool isQ3 = (q == 3);
    const int u0 = uOff[wv], u1 = uOff[wv + 1];

    if (!tail) {
        float pmax[4][2];
        #pragma unroll
        for (int nt = 0; nt < 4; ++nt) { pmax[nt][0] = NEGINF; pmax[nt][1] = NEGINF; }

        // rolled fused passes: ONE run_class_f inline site.
        #pragma unroll 1
        for (int iu = u0; iu < u1; ++iu) {
            const int r = uR[iu];
            run_class_f(xs, laneAB, wt + O64[r] + lane * 8,
                        tapsT[r], nwT[r], nhT[r], Bm, isQ3, pmax);
        }

        // ---- cross-wave reduction (P overlays xs; barrier first) ----
        __syncthreads();
        {
            int base = ((wv * 4 + q) * 16 + l) * 9;
            #pragma unroll
            for (int nt = 0; nt < 4; ++nt) {
                P[base + nt * 2 + 0] = pmax[nt][0];
                P[base + nt * 2 + 1] = pmax[nt][1];
            }
        }
        __syncthreads();

        for (int oi = threadIdx.x; oi < 320; oi += 256) {
            int co = oi / 5;
            int wjl = oi - co * 5;
            int lc = co & 15, ntc = co >> 4;
            float v = NEGINF;
            #pragma unroll
            for (int w = 0; w < 4; ++w) {
                #pragma unroll
                for (int qq = 0; qq < 4; ++qq) {
                    const float* pp = &P[((w * 4 + qq) * 16 + lc) * 9 + ntc * 2];
                    if (wjAt[qq] == wjl) v = fmaxf(v, pp[0]);
                    if (wjBt[qq] == wjl) v = fmaxf(v, pp[1]);
                }
            }
            Y[co * 5 + wjl] = v + bias[co];
        }
        __syncthreads();

        // channel-sum: wave 0, lane = co; 5 butterfly reductions over 64 lanes
        if (wv == 0) {
            float vy[5];
            #pragma unroll
            for (int wjl = 0; wjl < 5; ++wjl) vy[wjl] = Y[lane * 5 + wjl];
            #pragma unroll
            for (int wjl = 0; wjl < 5; ++wjl) {
                float v = vy[wjl];
                #pragma unroll
                for (int off = 32; off > 0; off >>= 1)
                    v += __shfl_down(v, off, 64);
                if (lane == 0)
                    out[((n * 5 + dj) * 10 + hj) * 10 + whalf * 5 + wjl] = v;
            }
        }
    } else {
        // ---- tail sub-block: all 8 fused units, single nt slice = sub ----
        float pmax1[2];
        pmax1[0] = NEGINF; pmax1[1] = NEGINF;

        #pragma unroll 1
        for (int iu = u0; iu < u1; ++iu) {
            const int r = uR[iu];
            run_class_t(xs, laneAB, wt + O64[r] + sub * 512 + lane * 8,
                        tapsT[r], nwT[r], nhT[r], Bm, isQ3, pmax1);
        }

        __syncthreads();
        {
            int base = ((wv * 4 + q) * 16 + l) * 9;
            P[base + sub * 2 + 0] = pmax1[0];
            P[base + sub * 2 + 1] = pmax1[1];
        }
        __syncthreads();

        // wave0: lane co in [sub*16, sub*16+16) holds a complete max; others 0.
        if (wv == 0) {
            const int co = lane;
            const int lc = co & 15, ntc = co >> 4;
            const bool valid = (ntc == sub);
            float vy[5];
            #pragma unroll
            for (int wjl = 0; wjl < 5; ++wjl) vy[wjl] = NEGINF;
            #pragma unroll
            for (int w = 0; w < 4; ++w) {
                #pragma unroll
                for (int qq = 0; qq < 4; ++qq) {
                    const float* pp = &P[((w * 4 + qq) * 16 + lc) * 9 + sub * 2];
                    float a = pp[0], bv = pp[1];
                    #pragma unroll
                    for (int wjl = 0; wjl < 5; ++wjl) {
                        if (wjAt[qq] == wjl) vy[wjl] = fmaxf(vy[wjl], a);
                        if (wjBt[qq] == wjl) vy[wjl] = fmaxf(vy[wjl], bv);
                    }
                }
            }
            #pragma unroll
            for (int wjl = 0; wjl < 5; ++wjl) {
                float v = valid ? (vy[wjl] + bias[co]) : 0.f;
                #pragma unroll
                for (int off = 32; off > 0; off >>= 1)
                    v += __shfl_down(v, off, 64);
                if (lane == 0)
                    atomicAdd(&out[((n * 5 + dj) * 10 + hj) * 10 + whalf * 5 + wjl], v);
            }
        }
    }
}

extern "C" void kernel_launch(void* const* d_in, const int* in_sizes, int n_in,
                              void* d_out, int out_size, void* d_ws, size_t ws_size,
                              hipStream_t stream) {
    const float* x    = (const float*)d_in[0];
    const float* w    = (const float*)d_in[1];
    const float* bias = (const float*)d_in[2];
    float*       out  = (float*)d_out;
    unsigned short* wt = (unsigned short*)d_ws;                        // 512000 B
    unsigned short* xp = (unsigned short*)((char*)d_ws + 512512);      // 18,382,848 B
    const size_t XP_NEED = 512512 + 18382848;
    const int do_x = (ws_size >= XP_NEED) ? 1 : 0;

    prep<<<dim3(2088), 256, 0, stream>>>(x, w, xp, wt, out, do_x);
    if (do_x)
        fused_main<true ><<<dim3(1792), 256, 0, stream>>>(x, xp, wt, bias, out);
    else
        fused_main<false><<<dim3(1792), 256, 0, stream>>>(x, xp, wt, bias, out);
}